// Round 1
// baseline (2290.511 us; speedup 1.0000x reference)
//
#include <hip/hip_runtime.h>
#include <stdint.h>

#define EMBED  256
#define HIDDEN 512
#define BATCH  64
#define SEQ    512

typedef _Float16 f16x8 __attribute__((ext_vector_type(8)));
typedef _Float16 f16x4 __attribute__((ext_vector_type(4)));
typedef float    f32x4 __attribute__((ext_vector_type(4)));

// ---------------------------------------------------------------------------
// Fragment packing convention (shared by A and B operands, permutation-safe):
//   frag[(s*NT + nt)*64 + lane] is an f16x8; element j holds
//     W[k = s*32 + (lane>>4)*8 + j][col = nt*16 + (lane&15)]
// MFMA 16x16x32: A rows on lane&15, B cols on lane&15, k-chunks on lane>>4.
// C/D (verified m89/m91): col = lane&15, row = (lane>>4)*4 + reg.
// ---------------------------------------------------------------------------

#define WIH_FRAGS (8 * 32 * 64 * 8)    // 131072 elems (K=256 -> s<8,  NT=32)
#define WHH_FRAGS (16 * 32 * 64 * 8)   // 262144 elems (K=512 -> s<16, NT=32)

__global__ void prep_pack(const float* __restrict__ W_ih,
                          const float* __restrict__ W_hh,
                          unsigned short* __restrict__ wih_p,
                          unsigned short* __restrict__ whh_p) {
    int tid = blockIdx.x * blockDim.x + threadIdx.x;
    if (tid < WIH_FRAGS) {
        int j = tid & 7, l = (tid >> 3) & 63, nt = (tid >> 9) & 31, s = tid >> 14;
        int k   = s * 32 + ((l >> 4) << 3) + j;
        int col = (nt << 4) + (l & 15);
        wih_p[tid] = __builtin_bit_cast(unsigned short, (_Float16)W_ih[k * HIDDEN + col]);
    } else {
        int t2 = tid - WIH_FRAGS;
        if (t2 < WHH_FRAGS) {
            int j = t2 & 7, l = (t2 >> 3) & 63, mt = (t2 >> 9) & 31, s = t2 >> 14;
            int k   = s * 32 + ((l >> 4) << 3) + j;
            int col = (mt << 4) + (l & 15);
            whh_p[t2] = __builtin_bit_cast(unsigned short, (_Float16)W_hh[k * HIDDEN + col]);
        }
    }
}

// ---------------------------------------------------------------------------
// Kernel A: pre[b,t,:] = embedding[source[b,t]] @ W_ih + (b_ih + b_hh)
// written into d_out (same shape as final output; kernel B overwrites in place)
// One wave per 16-row m-tile; 2048 tiles; B-frags from prepacked W_ih (L2).
// ---------------------------------------------------------------------------
__global__ __launch_bounds__(256) void enc_gemm_ih(
    const int* __restrict__ source,
    const float* __restrict__ embedding,
    const unsigned short* __restrict__ wih_p,
    const float* __restrict__ b_ih,
    const float* __restrict__ b_hh,
    float* __restrict__ out)
{
    const int lane = threadIdx.x & 63;
    const int mt   = (blockIdx.x << 2) + (threadIdx.x >> 6);  // m-tile 0..2047
    const int r0   = mt << 4;
    const int g    = lane >> 4;
    const int c    = lane & 15;

    const int idx = source[r0 + c];                 // this lane's row index
    const float* erow = embedding + (size_t)idx * EMBED;

    // A fragments: 8 k-slices of this wave's 16 rows, fp32 -> fp16 on the fly
    f16x8 afrag[8];
#pragma unroll
    for (int s = 0; s < 8; ++s) {
        const float* p = erow + (s << 5) + (g << 3);
        f32x4 f0 = *(const f32x4*)p;
        f32x4 f1 = *(const f32x4*)(p + 4);
        f16x8 a;
        a[0] = (_Float16)f0[0]; a[1] = (_Float16)f0[1];
        a[2] = (_Float16)f0[2]; a[3] = (_Float16)f0[3];
        a[4] = (_Float16)f1[0]; a[5] = (_Float16)f1[1];
        a[6] = (_Float16)f1[2]; a[7] = (_Float16)f1[3];
        afrag[s] = a;
    }

    const f16x8* wp = (const f16x8*)wih_p;
    for (int nt = 0; nt < 32; ++nt) {
        f32x4 acc = {0.f, 0.f, 0.f, 0.f};
#pragma unroll
        for (int s = 0; s < 8; ++s) {
            f16x8 b = wp[(((s << 5) + nt) << 6) + lane];
            acc = __builtin_amdgcn_mfma_f32_16x16x32_f16(afrag[s], b, acc, 0, 0, 0);
        }
        const int col  = (nt << 4) + c;
        const float bias = b_ih[col] + b_hh[col];
        float* o = out + (size_t)(r0 + (g << 2)) * HIDDEN + col;
#pragma unroll
        for (int r = 0; r < 4; ++r)
            o[(size_t)r * HIDDEN] = acc[r] + bias;   // C/D row = g*4+r
    }
}

// ---------------------------------------------------------------------------
// Kernel B: recurrence. 4 blocks x 16 chains (batch rows), 8 waves each.
// Operand-swapped MFMA: D[j, chain] = sum_k W_hh^T[j,k] * h[chain,k]
//   -> A = prepacked W_hh^T frags (from L2), B = h frags (from LDS).
// h double-buffered in LDS as fp16, row pad +8 (bank-balanced). One barrier/step.
// pre is read from d_out and overwritten with h in place.
// ---------------------------------------------------------------------------
__global__ __launch_bounds__(512) void enc_rnn(
    const unsigned short* __restrict__ whh_p,
    float* __restrict__ out)
{
    __shared__ unsigned short hbuf[2][16][HIDDEN + 8];

    const int tid  = threadIdx.x;
    const int lane = tid & 63;
    const int w    = tid >> 6;       // wave 0..7 -> owns j in [w*64, w*64+64)
    const int g    = lane >> 4;
    const int c    = lane & 15;      // chain within block

    for (int i = tid; i < 2 * 16 * (HIDDEN + 8); i += 512)
        ((unsigned short*)hbuf)[i] = 0;             // h_0 = 0
    __syncthreads();

    const int b = (blockIdx.x << 4) + c;            // batch row
    float* outb = out + (size_t)b * SEQ * HIDDEN;
    const f16x8* wp = (const f16x8*)whh_p;

    for (int t = 0; t < SEQ; ++t) {
        const int rb = t & 1;

        // B fragments: h_{t-1} for this lane's chain, all 16 k-slices
        f16x8 hfrag[16];
#pragma unroll
        for (int s = 0; s < 16; ++s)
            hfrag[s] = *(const f16x8*)&hbuf[rb][c][(s << 5) + (g << 3)];

        // pre-activations for this wave's 64 j's x this lane's chain (issue early)
        float* po = outb + (size_t)t * HIDDEN + (w << 6) + (g << 2);
        float pre[4][4];
#pragma unroll
        for (int m = 0; m < 4; ++m)
#pragma unroll
            for (int r = 0; r < 4; ++r)
                pre[m][r] = po[(m << 4) + r];

        f32x4 acc[4];
#pragma unroll
        for (int m = 0; m < 4; ++m) acc[m] = (f32x4){0.f, 0.f, 0.f, 0.f};

#pragma unroll
        for (int m = 0; m < 4; ++m) {
            const int mtg = (w << 2) + m;            // m-tile 0..31
#pragma unroll
            for (int s = 0; s < 16; ++s) {
                f16x8 a = wp[(((s << 5) + mtg) << 6) + lane];
                acc[m] = __builtin_amdgcn_mfma_f32_16x16x32_f16(a, hfrag[s], acc[m], 0, 0, 0);
            }
        }

        // epilogue: h = tanh(acc + pre); write fp32 to out, fp16 to LDS
#pragma unroll
        for (int m = 0; m < 4; ++m) {
            f16x4 hv4;
#pragma unroll
            for (int r = 0; r < 4; ++r) {
                float x  = acc[m][r] + pre[m][r];
                float e  = __expf(2.0f * x);
                float hv = 1.0f - 2.0f * __builtin_amdgcn_rcpf(e + 1.0f); // tanh(x)
                po[(m << 4) + r] = hv;
                hv4[r] = (_Float16)hv;
            }
            // j = w*64 + m*16 + g*4 + r -> 4 consecutive fp16 = one 8B write
            *(f16x4*)&hbuf[rb ^ 1][c][(w << 6) + (m << 4) + (g << 2)] = hv4;
        }
        __syncthreads();
    }
}

extern "C" void kernel_launch(void* const* d_in, const int* in_sizes, int n_in,
                              void* d_out, int out_size, void* d_ws, size_t ws_size,
                              hipStream_t stream) {
    const int*   source    = (const int*)d_in[0];
    const float* embedding = (const float*)d_in[1];
    const float* W_ih      = (const float*)d_in[2];
    const float* W_hh      = (const float*)d_in[3];
    const float* b_ih      = (const float*)d_in[4];
    const float* b_hh      = (const float*)d_in[5];
    float* out = (float*)d_out;

    unsigned short* wih_p = (unsigned short*)d_ws;          // 256 KB
    unsigned short* whh_p = wih_p + WIH_FRAGS;              // 512 KB

    const int prep_n = WIH_FRAGS + WHH_FRAGS;               // 393216
    prep_pack<<<prep_n / 256, 256, 0, stream>>>(W_ih, W_hh, wih_p, whh_p);
    enc_gemm_ih<<<(BATCH * SEQ / 16) / 4, 256, 0, stream>>>(source, embedding,
                                                            wih_p, b_ih, b_hh, out);
    enc_rnn<<<4, 512, 0, stream>>>(whh_p, out);
}

// Round 2
// 1299.438 us; speedup vs baseline: 1.7627x; 1.7627x over previous
//
#include <hip/hip_runtime.h>
#include <stdint.h>

#define EMBED  256
#define HIDDEN 512
#define BATCH  64
#define SEQ    512

typedef _Float16 f16x8 __attribute__((ext_vector_type(8)));
typedef _Float16 f16x4 __attribute__((ext_vector_type(4)));
typedef float    f32x4 __attribute__((ext_vector_type(4)));

// ---------------------------------------------------------------------------
// Fragment packing convention (shared by A and B operands, permutation-safe):
//   frag[(s*NT + nt)*64 + lane] is an f16x8; element j holds
//     W[k = s*32 + (lane>>4)*8 + j][col = nt*16 + (lane&15)]
// C/D (verified): col = lane&15, row = (lane>>4)*4 + reg.
// ---------------------------------------------------------------------------

#define WIH_FRAGS (8 * 32 * 64 * 8)    // 131072 elems (K=256 -> s<8,  NT=32)
#define WHH_FRAGS (16 * 32 * 64 * 8)   // 262144 elems (K=512 -> s<16, NT=32)

__global__ void prep_pack(const float* __restrict__ W_ih,
                          const float* __restrict__ W_hh,
                          unsigned short* __restrict__ wih_p,
                          unsigned short* __restrict__ whh_p) {
    int tid = blockIdx.x * blockDim.x + threadIdx.x;
    if (tid < WIH_FRAGS) {
        int j = tid & 7, l = (tid >> 3) & 63, nt = (tid >> 9) & 31, s = tid >> 14;
        int k   = s * 32 + ((l >> 4) << 3) + j;
        int col = (nt << 4) + (l & 15);
        wih_p[tid] = __builtin_bit_cast(unsigned short, (_Float16)W_ih[k * HIDDEN + col]);
    } else {
        int t2 = tid - WIH_FRAGS;
        if (t2 < WHH_FRAGS) {
            int j = t2 & 7, l = (t2 >> 3) & 63, mt = (t2 >> 9) & 31, s = t2 >> 14;
            int k   = s * 32 + ((l >> 4) << 3) + j;
            int col = (mt << 4) + (l & 15);
            whh_p[t2] = __builtin_bit_cast(unsigned short, (_Float16)W_hh[k * HIDDEN + col]);
        }
    }
}

// ---------------------------------------------------------------------------
// Kernel A: pre = embed @ W_ih + (b_ih + b_hh), stored as f16 in the HIGH 1KB
// of each 2KB out row (bytes [1024,2048)). The rnn kernel consumes it there.
// ---------------------------------------------------------------------------
__global__ __launch_bounds__(256) void enc_gemm_ih(
    const int* __restrict__ source,
    const float* __restrict__ embedding,
    const unsigned short* __restrict__ wih_p,
    const float* __restrict__ b_ih,
    const float* __restrict__ b_hh,
    float* __restrict__ out)
{
    const int lane = threadIdx.x & 63;
    const int mt   = (blockIdx.x << 2) + (threadIdx.x >> 6);  // m-tile 0..2047
    const int r0   = mt << 4;
    const int g    = lane >> 4;
    const int c    = lane & 15;

    const int idx = source[r0 + c];
    const float* erow = embedding + (size_t)idx * EMBED;

    f16x8 afrag[8];
#pragma unroll
    for (int s = 0; s < 8; ++s) {
        const float* p = erow + (s << 5) + (g << 3);
        f32x4 f0 = *(const f32x4*)p;
        f32x4 f1 = *(const f32x4*)(p + 4);
        f16x8 a;
        a[0] = (_Float16)f0[0]; a[1] = (_Float16)f0[1];
        a[2] = (_Float16)f0[2]; a[3] = (_Float16)f0[3];
        a[4] = (_Float16)f1[0]; a[5] = (_Float16)f1[1];
        a[6] = (_Float16)f1[2]; a[7] = (_Float16)f1[3];
        afrag[s] = a;
    }

    const f16x8* wp = (const f16x8*)wih_p;
    for (int nt = 0; nt < 32; ++nt) {
        f32x4 acc = {0.f, 0.f, 0.f, 0.f};
#pragma unroll
        for (int s = 0; s < 8; ++s) {
            f16x8 bfr = wp[(((s << 5) + nt) << 6) + lane];
            acc = __builtin_amdgcn_mfma_f32_16x16x32_f16(afrag[s], bfr, acc, 0, 0, 0);
        }
        const int col  = (nt << 4) + c;
        const float bias = b_ih[col] + b_hh[col];
        char* ob = (char*)out + (size_t)(r0 + (g << 2)) * 2048 + 1024 + (col << 1);
#pragma unroll
        for (int r = 0; r < 4; ++r)
            *(_Float16*)(ob + (size_t)r * 2048) = (_Float16)(acc[r] + bias);
    }
}

// ---------------------------------------------------------------------------
// Kernel B: recurrence. 4 blocks x 16 chains, 8 waves; wave w owns j in
// [w*64, w*64+64). W_hh tiers per wave: s=0..8 VGPR-resident (36 frags),
// s=9..11 LDS-resident (96KB), s=12..15 streamed from L2 (128KB/step).
// h double-buffered in LDS, XOR-swizzled 16B chunks (u ^= c&7), stride 1024B.
// pre read f16 from out row high half; h written f16 to out row low half.
// ---------------------------------------------------------------------------
__global__ __launch_bounds__(512, 2) void enc_rnn(
    const unsigned short* __restrict__ whh_p,
    float* __restrict__ out)
{
    extern __shared__ char lds[];
    char* hbase = lds;            // 32 KB: [2][16 rows][1024 B], swizzled
    char* wbase = lds + 32768;    // 96 KB: (w*12+fid)*1024 + lane*16

    const int tid  = threadIdx.x;
    const int lane = tid & 63;
    const int w    = tid >> 6;
    const int g    = lane >> 4;
    const int c    = lane & 15;
    const int cx   = c & 7;
    const int mtg0 = w << 2;

    const f16x8* wp = (const f16x8*)whh_p;

    // stage LDS-resident weights (s = 9..11)
    {
        char* wl = wbase + ((w * 12) << 10) + (lane << 4);
#pragma unroll
        for (int fid = 0; fid < 12; ++fid) {
            int s = 9 + (fid >> 2), m = fid & 3;
            f16x8 v = wp[((s * 32 + mtg0 + m) << 6) + lane];
            *(f16x8*)(wl + (fid << 10)) = v;
        }
    }
    // zero both h buffers (h_0 = 0)
    for (int i = tid; i < 32768 / 4; i += 512) ((int*)hbase)[i] = 0;

    // VGPR-resident weights (s = 0..8)
    f16x8 wreg[9][4];
#pragma unroll
    for (int s = 0; s < 9; ++s)
#pragma unroll
        for (int m = 0; m < 4; ++m)
            wreg[s][m] = wp[((s * 32 + mtg0 + m) << 6) + lane];

    __syncthreads();

    // ---- precomputed addresses (t-invariant) ----
    // h-read: logical chunk u = s*4+g, physical u^cx = ((s^(cx>>2))<<2)|(g^(cx&3))
    const int ch = cx >> 2;
    char* hb2  = hbase + (c << 10) + ((g ^ (cx & 3)) << 4);
    char* hbev = hb2 + (ch << 6);     // even s
    char* hbod = hb2 - (ch << 6);     // odd s
    // h-write: chunk = (w<<3) | ((m^(cx>>1))<<1) | ((g>>1)^(cx&1))
    char* hw[4];
#pragma unroll
    for (int m = 0; m < 4; ++m) {
        int chunk = (w << 3) | ((m ^ (cx >> 1)) << 1) | ((g >> 1) ^ (cx & 1));
        hw[m] = hbase + (c << 10) + (chunk << 4) + ((g & 1) << 3);
    }
    // global row slot: byte 2*j with j = w*64 + m*16 + g*4 (m via imm)
    const int b = (blockIdx.x << 4) + c;
    char* gaddr = (char*)out + (size_t)b * SEQ * (HIDDEN * 4) + (w << 7) + (g << 3);
    // streamed weight base pointers (s = 12..15), m*1024 as imm offset
    const char* sp[4];
#pragma unroll
    for (int s = 0; s < 4; ++s)
        sp[s] = (const char*)whh_p + (((12 + s) * 32 + mtg0) << 10) + (lane << 4);
    char* wl = wbase + ((w * 12) << 10) + (lane << 4);

    auto STEP = [&](int RB, int RBN, int TB) {
        // issue streamed loads for s=12, s=13 (consumed ~40 MFMAs later)
        f16x8 sA[4], sB[4];
#pragma unroll
        for (int m = 0; m < 4; ++m) sA[m] = *(const f16x8*)(sp[0] + (m << 10));
#pragma unroll
        for (int m = 0; m < 4; ++m) sB[m] = *(const f16x8*)(sp[1] + (m << 10));
        // pre-activations (f16) for this wave's 64 j's
        f16x4 pre[4];
#pragma unroll
        for (int m = 0; m < 4; ++m)
            pre[m] = *(const f16x4*)(gaddr + TB + 1024 + (m << 5));

        f32x4 acc[4];
#pragma unroll
        for (int m = 0; m < 4; ++m) acc[m] = (f32x4){0.f, 0.f, 0.f, 0.f};

        // s = 0..8: VGPR weights
#pragma unroll
        for (int s = 0; s < 9; ++s) {
            f16x8 h = *(const f16x8*)(((s & 1) ? hbod : hbev) + (s << 6) + RB);
#pragma unroll
            for (int m = 0; m < 4; ++m)
                acc[m] = __builtin_amdgcn_mfma_f32_16x16x32_f16(wreg[s][m], h, acc[m], 0, 0, 0);
        }
        // s = 9..11: LDS weights
#pragma unroll
        for (int s = 9; s < 12; ++s) {
            f16x8 h = *(const f16x8*)(((s & 1) ? hbod : hbev) + (s << 6) + RB);
#pragma unroll
            for (int m = 0; m < 4; ++m) {
                f16x8 wv = *(const f16x8*)(wl + ((((s - 9) << 2) | m) << 10));
                acc[m] = __builtin_amdgcn_mfma_f32_16x16x32_f16(wv, h, acc[m], 0, 0, 0);
            }
        }
        // s = 12 (sA), then refill sA <- s14
        {
            f16x8 h = *(const f16x8*)(hbev + (12 << 6) + RB);
#pragma unroll
            for (int m = 0; m < 4; ++m)
                acc[m] = __builtin_amdgcn_mfma_f32_16x16x32_f16(sA[m], h, acc[m], 0, 0, 0);
        }
#pragma unroll
        for (int m = 0; m < 4; ++m) sA[m] = *(const f16x8*)(sp[2] + (m << 10));
        // s = 13 (sB), then refill sB <- s15
        {
            f16x8 h = *(const f16x8*)(hbod + (13 << 6) + RB);
#pragma unroll
            for (int m = 0; m < 4; ++m)
                acc[m] = __builtin_amdgcn_mfma_f32_16x16x32_f16(sB[m], h, acc[m], 0, 0, 0);
        }
#pragma unroll
        for (int m = 0; m < 4; ++m) sB[m] = *(const f16x8*)(sp[3] + (m << 10));
        // s = 14 (sA)
        {
            f16x8 h = *(const f16x8*)(hbev + (14 << 6) + RB);
#pragma unroll
            for (int m = 0; m < 4; ++m)
                acc[m] = __builtin_amdgcn_mfma_f32_16x16x32_f16(sA[m], h, acc[m], 0, 0, 0);
        }
        // s = 15 (sB)
        {
            f16x8 h = *(const f16x8*)(hbod + (15 << 6) + RB);
#pragma unroll
            for (int m = 0; m < 4; ++m)
                acc[m] = __builtin_amdgcn_mfma_f32_16x16x32_f16(sB[m], h, acc[m], 0, 0, 0);
        }

        // epilogue: h = tanh(acc + pre); f16 to out row low half + LDS next buf
#pragma unroll
        for (int m = 0; m < 4; ++m) {
            f16x4 hv;
#pragma unroll
            for (int r = 0; r < 4; ++r) {
                float x  = acc[m][r] + (float)pre[m][r];
                float e  = __expf(2.0f * x);
                float th = 1.0f - 2.0f * __builtin_amdgcn_rcpf(e + 1.0f); // tanh
                hv[r] = (_Float16)th;
            }
            *(f16x4*)(gaddr + TB + (m << 5)) = hv;
            *(f16x4*)(hw[m] + RBN) = hv;
        }
        __syncthreads();
    };

#pragma unroll 1
    for (int tp = 0; tp < SEQ; tp += 2) {
        STEP(0, 16384, 0);
        STEP(16384, 0, 2048);
        gaddr += 4096;
    }
}

// ---------------------------------------------------------------------------
// Kernel C: in-place expand f16 h (row bytes [0,1024)) -> f32 (bytes [0,2048)).
// One wave per row: all 64 lanes load before any store (per-wave program order).
// ---------------------------------------------------------------------------
__global__ __launch_bounds__(256) void expand_rows(float* __restrict__ out) {
    const int lane = threadIdx.x & 63;
    const int row  = (blockIdx.x << 2) + (threadIdx.x >> 6);
    char* rp = (char*)out + ((size_t)row << 11);
    f16x8 v = *(const f16x8*)(rp + (lane << 4));
    f32x4 lo, hi;
#pragma unroll
    for (int i = 0; i < 4; ++i) { lo[i] = (float)v[i]; hi[i] = (float)v[i + 4]; }
    *(f32x4*)(rp + (lane << 5))      = lo;
    *(f32x4*)(rp + (lane << 5) + 16) = hi;
}

extern "C" void kernel_launch(void* const* d_in, const int* in_sizes, int n_in,
                              void* d_out, int out_size, void* d_ws, size_t ws_size,
                              hipStream_t stream) {
    const int*   source    = (const int*)d_in[0];
    const float* embedding = (const float*)d_in[1];
    const float* W_ih      = (const float*)d_in[2];
    const float* W_hh      = (const float*)d_in[3];
    const float* b_ih      = (const float*)d_in[4];
    const float* b_hh      = (const float*)d_in[5];
    float* out = (float*)d_out;

    unsigned short* wih_p = (unsigned short*)d_ws;          // 256 KB
    unsigned short* whh_p = wih_p + WIH_FRAGS;              // 512 KB

    prep_pack<<<(WIH_FRAGS + WHH_FRAGS) / 256, 256, 0, stream>>>(W_ih, W_hh, wih_p, whh_p);
    enc_gemm_ih<<<512, 256, 0, stream>>>(source, embedding, wih_p, b_ih, b_hh, out);
    enc_rnn<<<4, 512, 131072, stream>>>(whh_p, out);
    expand_rows<<<8192, 256, 0, stream>>>(out);
}

// Round 3
// 1082.200 us; speedup vs baseline: 2.1165x; 1.2007x over previous
//
#include <hip/hip_runtime.h>
#include <stdint.h>

#define EMBED  256
#define HIDDEN 512
#define BATCH  64
#define SEQ    512

typedef _Float16 f16x8 __attribute__((ext_vector_type(8)));
typedef _Float16 f16x4 __attribute__((ext_vector_type(4)));
typedef float    f32x4 __attribute__((ext_vector_type(4)));

// ---------------------------------------------------------------------------
// Fragment packing (A and B share it; permutation-safe):
//   frag[(s*32 + mt)*64 + lane] is an f16x8; element j holds
//     W[k = s*32 + (lane>>4)*8 + j][col = mt*16 + (lane&15)]
// C/D: col = lane&15, row = (lane>>4)*4 + reg.
// ---------------------------------------------------------------------------

#define WIH_FRAGS (8 * 32 * 64 * 8)
#define WHH_FRAGS (16 * 32 * 64 * 8)

__global__ void prep_pack(const float* __restrict__ W_ih,
                          const float* __restrict__ W_hh,
                          unsigned short* __restrict__ wih_p,
                          unsigned short* __restrict__ whh_p) {
    int tid = blockIdx.x * blockDim.x + threadIdx.x;
    if (tid < WIH_FRAGS) {
        int j = tid & 7, l = (tid >> 3) & 63, nt = (tid >> 9) & 31, s = tid >> 14;
        int k   = s * 32 + ((l >> 4) << 3) + j;
        int col = (nt << 4) + (l & 15);
        wih_p[tid] = __builtin_bit_cast(unsigned short, (_Float16)W_ih[k * HIDDEN + col]);
    } else {
        int t2 = tid - WIH_FRAGS;
        if (t2 < WHH_FRAGS) {
            int j = t2 & 7, l = (t2 >> 3) & 63, mt = (t2 >> 9) & 31, s = t2 >> 14;
            int k   = s * 32 + ((l >> 4) << 3) + j;
            int col = (mt << 4) + (l & 15);
            whh_p[t2] = __builtin_bit_cast(unsigned short, (_Float16)W_hh[k * HIDDEN + col]);
        }
    }
}

// ---------------------------------------------------------------------------
// Kernel A: pre = embed @ W_ih + (b_ih + b_hh), f16 in HIGH 1KB of each 2KB
// out row. (unchanged from R2)
// ---------------------------------------------------------------------------
__global__ __launch_bounds__(256) void enc_gemm_ih(
    const int* __restrict__ source,
    const float* __restrict__ embedding,
    const unsigned short* __restrict__ wih_p,
    const float* __restrict__ b_ih,
    const float* __restrict__ b_hh,
    float* __restrict__ out)
{
    const int lane = threadIdx.x & 63;
    const int mt   = (blockIdx.x << 2) + (threadIdx.x >> 6);
    const int r0   = mt << 4;
    const int g    = lane >> 4;
    const int c    = lane & 15;

    const int idx = source[r0 + c];
    const float* erow = embedding + (size_t)idx * EMBED;

    f16x8 afrag[8];
#pragma unroll
    for (int s = 0; s < 8; ++s) {
        const float* p = erow + (s << 5) + (g << 3);
        f32x4 f0 = *(const f32x4*)p;
        f32x4 f1 = *(const f32x4*)(p + 4);
        f16x8 a;
        a[0] = (_Float16)f0[0]; a[1] = (_Float16)f0[1];
        a[2] = (_Float16)f0[2]; a[3] = (_Float16)f0[3];
        a[4] = (_Float16)f1[0]; a[5] = (_Float16)f1[1];
        a[6] = (_Float16)f1[2]; a[7] = (_Float16)f1[3];
        afrag[s] = a;
    }

    const f16x8* wp = (const f16x8*)wih_p;
    for (int nt = 0; nt < 32; ++nt) {
        f32x4 acc = {0.f, 0.f, 0.f, 0.f};
#pragma unroll
        for (int s = 0; s < 8; ++s) {
            f16x8 bfr = wp[(((s << 5) + nt) << 6) + lane];
            acc = __builtin_amdgcn_mfma_f32_16x16x32_f16(afrag[s], bfr, acc, 0, 0, 0);
        }
        const int col  = (nt << 4) + c;
        const float bias = b_ih[col] + b_hh[col];
        char* ob = (char*)out + (size_t)(r0 + (g << 2)) * 2048 + 1024 + (col << 1);
#pragma unroll
        for (int r = 0; r < 4; ++r)
            *(_Float16*)(ob + (size_t)r * 2048) = (_Float16)(acc[r] + bias);
    }
}

// ---------------------------------------------------------------------------
// Kernel B: recurrence. 8 blocks x 8 chains, 8 waves; wave w owns j in
// [w*64, w*64+64). MFMA cols 8..15 duplicate cols 0..7 (ignored).
// W_hh tiers per wave: VGPR 34 frags (s0..7 all m, s8 m0..1);
// LDS 18 frags (s8 m2..3, s9..12) = 144KB; stream s13..15 (96KB/step).
// h double-buffered in LDS [2][8][1024B], XOR-swizzled 16B chunks (u ^ cc).
// ---------------------------------------------------------------------------
__global__ __launch_bounds__(512, 1) void enc_rnn(
    const unsigned short* __restrict__ whh_p,
    float* __restrict__ out)
{
    extern __shared__ char lds[];
    char* hbase = lds;            // 16 KB: [2][8 rows][1024 B], swizzled
    char* wbase = lds + 16384;    // 144 KB: (w*18 + fid)*1024 + lane*16

    const int tid  = threadIdx.x;
    const int lane = tid & 63;
    const int w    = tid >> 6;
    const int g    = lane >> 4;
    const int c    = lane & 15;      // D column
    const int cc   = lane & 7;       // chain (rows 8..15 duplicate)
    const bool cvalid = (c < 8);
    const int mtg0 = w << 2;

    const f16x8* wp = (const f16x8*)whh_p;

    // stage LDS-tier weights: fid 0,1 -> (s8,m2),(s8,m3); fid>=2 -> s=9+(fid-2)/4
    {
        char* wl = wbase + ((w * 18) << 10) + (lane << 4);
#pragma unroll
        for (int fid = 0; fid < 18; ++fid) {
            int s = (fid < 2) ? 8 : 9 + ((fid - 2) >> 2);
            int m = (fid < 2) ? 2 + fid : ((fid - 2) & 3);
            f16x8 v = wp[((s * 32 + mtg0 + m) << 6) + lane];
            *(f16x8*)(wl + (fid << 10)) = v;
        }
    }
    // zero both h buffers (h_0 = 0)
    for (int i = tid; i < 16384 / 4; i += 512) ((int*)hbase)[i] = 0;

    // VGPR-tier weights: s0..7 all m (idx s*4+m) + s8 m0,m1 (idx 32+m)
    f16x8 wreg[34];
#pragma unroll
    for (int s = 0; s < 8; ++s)
#pragma unroll
        for (int m = 0; m < 4; ++m)
            wreg[s * 4 + m] = wp[((s * 32 + mtg0 + m) << 6) + lane];
#pragma unroll
    for (int m = 0; m < 2; ++m)
        wreg[32 + m] = wp[((8 * 32 + mtg0 + m) << 6) + lane];

    __syncthreads();

    // ---- t-invariant addresses ----
    // h-read (chunk u = 4s+g, phys = u ^ cc):
    //   addr = cc*1024 + (s>>1)*128 + ((s&1)^(cc>>2))*64 + (g^(cc&3))*16
    char* hev = hbase + (cc << 10) + ((cc >> 2) << 6) + ((g ^ (cc & 3)) << 4);
    char* hod = hbase + (cc << 10) + (((cc >> 2) ^ 1) << 6) + ((g ^ (cc & 3)) << 4);
    // h-write (chunk u = w*8 + m*2 + (g>>1), phys = u ^ cc):
    char* hw[4];
#pragma unroll
    for (int m = 0; m < 4; ++m) {
        int u = (w << 3) + (m << 1) + (g >> 1);
        hw[m] = hbase + (cc << 10) + ((u ^ cc) << 4) + ((g & 1) << 3);
    }
    // global row: chain b = bg*8+cc; slot byte 2*j, j = w*64 + m*16 + g*4
    char* ga = (char*)out + (size_t)((blockIdx.x << 3) + cc) * SEQ * 2048
             + (w << 7) + (g << 3);
    // stream bases (s = 13..15)
    const char* sp0 = (const char*)whh_p + ((13 * 32 + mtg0) << 10) + (lane << 4);
    const char* sp1 = (const char*)whh_p + ((14 * 32 + mtg0) << 10) + (lane << 4);
    const char* sp2 = (const char*)whh_p + ((15 * 32 + mtg0) << 10) + (lane << 4);
    char* wl = wbase + ((w * 18) << 10) + (lane << 4);

    auto STEP = [&](int RB, int RBN, int TB) {
        // stream s13, s14 now; pre-activations now
        f16x8 sA[4], sB[4], sC[4];
#pragma unroll
        for (int m = 0; m < 4; ++m) sA[m] = *(const f16x8*)(sp0 + (m << 10));
#pragma unroll
        for (int m = 0; m < 4; ++m) sB[m] = *(const f16x8*)(sp1 + (m << 10));
        f16x4 pre[4];
#pragma unroll
        for (int m = 0; m < 4; ++m)
            pre[m] = *(const f16x4*)(ga + TB + 1024 + (m << 5));

        f32x4 acc[4];
#pragma unroll
        for (int m = 0; m < 4; ++m) acc[m] = (f32x4){0.f, 0.f, 0.f, 0.f};

        f16x8 hh[16];
        hh[0] = *(const f16x8*)(hev + RB);
        hh[1] = *(const f16x8*)(hod + (0 << 7) + RB);
#pragma unroll
        for (int s = 0; s < 16; ++s) {
            if (s + 2 < 16) {
                int sn = s + 2;
                hh[sn] = *(const f16x8*)(((sn & 1) ? hod : hev) + ((sn >> 1) << 7) + RB);
            }
            if (s == 9) {   // issue s15 stream mid-flight
#pragma unroll
                for (int m = 0; m < 4; ++m) sC[m] = *(const f16x8*)(sp2 + (m << 10));
            }
#pragma unroll
            for (int m = 0; m < 4; ++m) {
                f16x8 wv;
                if (s < 8)            wv = wreg[s * 4 + m];
                else if (s == 8 && m < 2) wv = wreg[32 + m];
                else if (s == 8)      wv = *(const f16x8*)(wl + ((m - 2) << 10));
                else if (s < 13)      wv = *(const f16x8*)(wl + ((2 + ((s - 9) << 2) + m) << 10));
                else if (s == 13)     wv = sA[m];
                else if (s == 14)     wv = sB[m];
                else                  wv = sC[m];
                acc[m] = __builtin_amdgcn_mfma_f32_16x16x32_f16(wv, hh[s], acc[m], 0, 0, 0);
            }
        }

        // epilogue: h = tanh(acc + pre)
#pragma unroll
        for (int m = 0; m < 4; ++m) {
            f16x4 hv;
#pragma unroll
            for (int r = 0; r < 4; ++r) {
                float x  = acc[m][r] + (float)pre[m][r];
                float e  = __expf(2.0f * x);
                float th = 1.0f - 2.0f * __builtin_amdgcn_rcpf(e + 1.0f);
                hv[r] = (_Float16)th;
            }
            if (cvalid) {
                *(f16x4*)(ga + TB + (m << 5)) = hv;
                *(f16x4*)(hw[m] + RBN) = hv;
            }
        }
        __syncthreads();
    };

#pragma unroll 1
    for (int tp = 0; tp < SEQ; tp += 2) {
        STEP(0, 8192, 0);
        STEP(8192, 0, 2048);
        ga += 4096;
    }
}

// ---------------------------------------------------------------------------
// Kernel C: in-place expand f16 h (row bytes [0,1024)) -> f32 row.
// ---------------------------------------------------------------------------
__global__ __launch_bounds__(256) void expand_rows(float* __restrict__ out) {
    const int lane = threadIdx.x & 63;
    const int row  = (blockIdx.x << 2) + (threadIdx.x >> 6);
    char* rp = (char*)out + ((size_t)row << 11);
    f16x8 v = *(const f16x8*)(rp + (lane << 4));
    f32x4 lo, hi;
#pragma unroll
    for (int i = 0; i < 4; ++i) { lo[i] = (float)v[i]; hi[i] = (float)v[i + 4]; }
    *(f32x4*)(rp + (lane << 5))      = lo;
    *(f32x4*)(rp + (lane << 5) + 16) = hi;
}

extern "C" void kernel_launch(void* const* d_in, const int* in_sizes, int n_in,
                              void* d_out, int out_size, void* d_ws, size_t ws_size,
                              hipStream_t stream) {
    const int*   source    = (const int*)d_in[0];
    const float* embedding = (const float*)d_in[1];
    const float* W_ih      = (const float*)d_in[2];
    const float* W_hh      = (const float*)d_in[3];
    const float* b_ih      = (const float*)d_in[4];
    const float* b_hh      = (const float*)d_in[5];
    float* out = (float*)d_out;

    unsigned short* wih_p = (unsigned short*)d_ws;          // 256 KB
    unsigned short* whh_p = wih_p + WIH_FRAGS;              // 512 KB

    prep_pack<<<(WIH_FRAGS + WHH_FRAGS) / 256, 256, 0, stream>>>(W_ih, W_hh, wih_p, whh_p);
    enc_gemm_ih<<<512, 256, 0, stream>>>(source, embedding, wih_p, b_ih, b_hh, out);
    enc_rnn<<<8, 512, 163840, stream>>>(whh_p, out);
    expand_rows<<<8192, 256, 0, stream>>>(out);
}